// Round 10
// baseline (156.421 us; speedup 1.0000x reference)
//
#include <hip/hip_runtime.h>

using f16x8 = __attribute__((ext_vector_type(8))) _Float16;
using f16x4 = __attribute__((ext_vector_type(4))) _Float16;
using f32x4 = __attribute__((ext_vector_type(4))) float;

#define T_SEQ 2048
#define D_MODEL 512
#define NH 8
#define HD 64
#define NB 2
#define M_ROWS (NB * T_SEQ)   // 4096
#define NBLK 512              // mega grid size (2 blocks/CU by capacity)

// async global->LDS, 16B per lane. LDS dest must be wave-uniform base;
// HW adds lane*16. Source is per-lane.
#define GLOAD_LDS16(g, l)                                              \
  __builtin_amdgcn_global_load_lds(                                    \
      (const __attribute__((address_space(1))) void*)(g),              \
      (__attribute__((address_space(3))) void*)(l), 16, 0, 0)

// ---------------------------------------------------------------- grid barrier
// Single-use slot per phase boundary. Arrive: fetch_add(RELEASE) (one L2
// writeback). Spin: RELAXED loads only (NO per-poll cache maintenance —
// the acquire-poll invalidate storm was R8/R9's 80-100us failure). Exit:
// one ACQUIRE load per block (one invalidate). Slots 128B apart.
__device__ __forceinline__ void gridbar(int* __restrict__ flags, int slot,
                                        int tid) {
  __syncthreads();
  if (tid == 0) {
    __hip_atomic_fetch_add(&flags[slot * 32], 1, __ATOMIC_RELEASE,
                           __HIP_MEMORY_SCOPE_AGENT);
    while (__hip_atomic_load(&flags[slot * 32], __ATOMIC_RELAXED,
                             __HIP_MEMORY_SCOPE_AGENT) < NBLK)
      __builtin_amdgcn_s_sleep(2);
    (void)__hip_atomic_load(&flags[slot * 32], __ATOMIC_ACQUIRE,
                            __HIP_MEMORY_SCOPE_AGENT);
  }
  __syncthreads();
}

// ---------------------------------------------------------------- GEMM phase
// C[m][n] = sum_k A[m][k] * Bt[n][k] + bias[n]
// 3-buffer 2-deep prefetch, counted vmcnt (T3+T4); LDS XOR-swizzle via
// pre-swizzled global source + swizzled reads (T2 both-sides involution).
template <int OUT_F32, int BM, int BN, int WR>
__device__ __forceinline__ void gemm_phase(
    char* smraw, const _Float16* __restrict__ A,
    const _Float16* __restrict__ Bt, const float* __restrict__ bias,
    void* __restrict__ outBase, int m0, int n0, int tid) {
  constexpr int WC = 4 / WR;
  constexpr int MF = BM / WR / 16;
  constexpr int NF = BN / WC / 16;
  constexpr int NT = D_MODEL / 32;            // 16 K-steps
  constexpr int LPS = BM / 64 + BN / 64;      // gload_lds per thread/stage
  _Float16* At = (_Float16*)smraw;
  _Float16* Bts = (_Float16*)(smraw + 3 * BM * 32 * 2);
  const int l = tid & 63;
  const int wv = tid >> 6;
  const int wm = wv / WC, wn = wv % WC;
  const int r16 = l & 15, g4 = l >> 4;
  f32x4 acc[MF][NF] = {};

  auto stage = [&](int bb, int k0) {
#pragma unroll
    for (int cc = 0; cc < BM / 64; ++cc) {
      int c = tid + cc * 256;
      int row = c >> 2, sp = (c & 3) ^ (row & 3);
      GLOAD_LDS16(&A[(size_t)(m0 + row) * D_MODEL + k0 + sp * 8],
                  &At[bb * BM * 32 + (c - l) * 8]);
    }
#pragma unroll
    for (int cc = 0; cc < BN / 64; ++cc) {
      int c = tid + cc * 256;
      int row = c >> 2, sp = (c & 3) ^ (row & 3);
      GLOAD_LDS16(&Bt[(size_t)(n0 + row) * D_MODEL + k0 + sp * 8],
                  &Bts[bb * BN * 32 + (c - l) * 8]);
    }
  };
  auto compute = [&](int bb) {
    f16x8 a[MF], b[NF];
#pragma unroll
    for (int mf = 0; mf < MF; ++mf) {
      int row = wm * (BM / WR) + mf * 16 + r16;
      a[mf] =
          *(const f16x8*)&At[bb * BM * 32 + row * 32 + (g4 ^ (row & 3)) * 8];
    }
#pragma unroll
    for (int nf = 0; nf < NF; ++nf) {
      int row = wn * (BN / WC) + nf * 16 + r16;
      b[nf] =
          *(const f16x8*)&Bts[bb * BN * 32 + row * 32 + (g4 ^ (row & 3)) * 8];
    }
#pragma unroll
    for (int mf = 0; mf < MF; ++mf)
#pragma unroll
      for (int nf = 0; nf < NF; ++nf)
        acc[mf][nf] = __builtin_amdgcn_mfma_f32_16x16x32_f16(
            a[mf], b[nf], acc[mf][nf], 0, 0, 0);
  };

  __syncthreads();   // guard LDS reuse across phases
  stage(0, 0);
  stage(1, 32);
#pragma unroll
  for (int t = 0; t < NT; ++t) {
    if (t + 1 < NT)
      asm volatile("s_waitcnt vmcnt(%0)" ::"n"(LPS) : "memory");
    else
      asm volatile("s_waitcnt vmcnt(0)" ::: "memory");
    __builtin_amdgcn_s_barrier();
    compute(t % 3);
    if (t + 2 < NT) stage((t + 2) % 3, (t + 2) * 32);
  }

#pragma unroll
  for (int mf = 0; mf < MF; ++mf) {
#pragma unroll
    for (int nf = 0; nf < NF; ++nf) {
      int col = n0 + wn * (BN / WC) + nf * 16 + r16;
      float bs = bias[col];
#pragma unroll
      for (int r = 0; r < 4; ++r) {
        int rowi = m0 + wm * (BM / WR) + mf * 16 + g4 * 4 + r;
        float v = acc[mf][nf][r] + bs;
        if (OUT_F32)
          ((float*)outBase)[(size_t)rowi * D_MODEL + col] = v;
        else
          ((_Float16*)outBase)[(size_t)rowi * D_MODEL + col] = (_Float16)v;
      }
    }
  }
}

// ---------------------------------------------------------------- attn phase
// keys j=0..127 map to t = k0+j; window for query ql: j in [ql, ql+64].
// OOB keys are zero (score 0 in softmax denom = reference zero-pad).
__device__ __forceinline__ void attn_phase(
    char* smraw, const _Float16* __restrict__ Q, const _Float16* __restrict__ K,
    const _Float16* __restrict__ V, _Float16* __restrict__ att, int b, int h,
    int t0, int tid) {
  _Float16* Ks = (_Float16*)smraw;                     // 128*64
  _Float16* Vt = (_Float16*)(smraw + 16384);           // 64*136
  _Float16* Ps = (_Float16*)(smraw + 16384 + 17408);   // 64*136
  const int k0 = t0 - 32;
  const int l = tid & 63;
  const int wv = tid >> 6;
  const int r16 = l & 15, g4 = l >> 4;
  const size_t colbase = (size_t)h * HD;
  __syncthreads();   // guard LDS reuse across phases
  // Q fragments straight to registers
  f16x8 qf[2];
#pragma unroll
  for (int kk = 0; kk < 2; ++kk)
    qf[kk] = *(const f16x8*)&Q[(size_t)(b * T_SEQ + t0 + wv * 16 + r16) *
                                   D_MODEL + colbase + kk * 32 + g4 * 8];
  // stage K: interior DMA (pre-swizzled source), edge reg path
  const bool interior = (k0 >= 0) && (k0 + 128 <= T_SEQ);
  if (interior) {
#pragma unroll
    for (int cc = 0; cc < 4; ++cc) {
      int c = tid + cc * 256;
      int row = c >> 3, part = c & 7;
      int sp = part ^ (row & 7);
      GLOAD_LDS16(
          &K[(size_t)(b * T_SEQ + k0 + row) * D_MODEL + colbase + sp * 8],
          &Ks[(c - l) * 8]);
    }
  } else {
#pragma unroll
    for (int cc = 0; cc < 4; ++cc) {
      int c = tid + cc * 256;
      int row = c >> 3, part = c & 7;
      int t = k0 + row;
      f16x8 v = {};
      if (t >= 0 && t < T_SEQ)
        v = *(const f16x8*)&K[(size_t)(b * T_SEQ + t) * D_MODEL + colbase +
                              part * 8];
      *(f16x8*)&Ks[row * 64 + (part ^ (row & 7)) * 8] = v;
    }
  }
  // stage V transposed: Vt[dd][key], padded stride 136
#pragma unroll
  for (int cc = 0; cc < 4; ++cc) {
    int c = tid + cc * 256;
    int row = c >> 3, part = c & 7;
    int t = k0 + row;
    f16x8 v = {};
    if (t >= 0 && t < T_SEQ)
      v = *(const f16x8*)&V[(size_t)(b * T_SEQ + t) * D_MODEL + colbase +
                            part * 8];
#pragma unroll
    for (int j = 0; j < 8; ++j) Vt[(part * 8 + j) * 136 + row] = v[j];
  }
  __syncthreads();
  // S = Q K^T : wave wv owns query rows [wv*16, wv*16+16), all 128 keys
  f32x4 s[8] = {};
#pragma unroll
  for (int kk = 0; kk < 2; ++kk) {
    int pp = kk * 4 + g4;
#pragma unroll
    for (int nf = 0; nf < 8; ++nf) {
      f16x8 bb =
          *(const f16x8*)&Ks[(nf * 16 + r16) * 64 + (pp ^ (r16 & 7)) * 8];
      s[nf] =
          __builtin_amdgcn_mfma_f32_16x16x32_f16(qf[kk], bb, s[nf], 0, 0, 0);
    }
  }
  // softmax: lane's rows ql = wv*16 + g4*4 + r ; cols j = nf*16 + r16
#pragma unroll
  for (int r = 0; r < 4; ++r) {
    int ql = wv * 16 + g4 * 4 + r;
    float vals[8];
    float m = -1e30f;
#pragma unroll
    for (int nf = 0; nf < 8; ++nf) {
      int j = nf * 16 + r16;
      bool in = (j >= ql) && (j <= ql + 64);
      float sv = in ? s[nf][r] * 0.125f : -1e30f;
      vals[nf] = sv;
      m = fmaxf(m, sv);
    }
#pragma unroll
    for (int off = 1; off < 16; off <<= 1) m = fmaxf(m, __shfl_xor(m, off, 64));
    float e[8];
    float sum = 0.f;
#pragma unroll
    for (int nf = 0; nf < 8; ++nf) {
      float ev = (vals[nf] > -1e29f) ? __expf(vals[nf] - m) : 0.f;
      e[nf] = ev;
      sum += ev;
    }
#pragma unroll
    for (int off = 1; off < 16; off <<= 1) sum += __shfl_xor(sum, off, 64);
    float inv = 1.f / sum;
#pragma unroll
    for (int nf = 0; nf < 8; ++nf)
      Ps[ql * 136 + nf * 16 + r16] = (_Float16)(e[nf] * inv);
  }
  __syncthreads();
  // O = P V
  f32x4 o[4] = {};
#pragma unroll
  for (int kk = 0; kk < 4; ++kk) {
    f16x8 a = *(const f16x8*)&Ps[(wv * 16 + r16) * 136 + kk * 32 + g4 * 8];
#pragma unroll
    for (int nf = 0; nf < 4; ++nf) {
      f16x8 bb = *(const f16x8*)&Vt[(nf * 16 + r16) * 136 + kk * 32 + g4 * 8];
      o[nf] = __builtin_amdgcn_mfma_f32_16x16x32_f16(a, bb, o[nf], 0, 0, 0);
    }
  }
#pragma unroll
  for (int nf = 0; nf < 4; ++nf)
#pragma unroll
    for (int r = 0; r < 4; ++r) {
      int row = t0 + wv * 16 + g4 * 4 + r;
      int col = nf * 16 + r16;
      att[(size_t)(b * T_SEQ + row) * D_MODEL + colbase + col] =
          (_Float16)o[nf][r];
    }
}

// ---------------------------------------------------------------- mega kernel
// 512 blocks x 256 threads (2 blocks/CU by capacity: 50KB LDS, 96 VGPR).
// Phase boundaries via the relaxed-spin grid barrier above (NOT grid.sync,
// NOT acquire-polling — both measured 80-100us/barrier from invalidate storms).
__global__ __launch_bounds__(256, 2) void mega(
    const float* __restrict__ x, const float* __restrict__ wq,
    const float* __restrict__ wk, const float* __restrict__ wv,
    const float* __restrict__ wo, const float* __restrict__ bq,
    const float* __restrict__ bk, const float* __restrict__ bv,
    const float* __restrict__ bo, float* __restrict__ out,
    _Float16* __restrict__ xh, _Float16* __restrict__ wT,
    float* __restrict__ bias3, _Float16* __restrict__ QKV,
    _Float16* __restrict__ att, int* __restrict__ flags) {
  __shared__ __align__(16) char smraw[51200];
  const int bid = blockIdx.x;
  const int tid = threadIdx.x;

  // ---- phase 0: x -> fp16 (4 chunks/block); weight transpose (2 tiles)
  {
#pragma unroll
    for (int u = 0; u < 4; ++u) {
      int idx = ((bid * 4 + u) * 256 + tid) * 4;
      float4 v = *(const float4*)(x + idx);
      f16x4 h4;
      h4[0] = (_Float16)v.x; h4[1] = (_Float16)v.y;
      h4[2] = (_Float16)v.z; h4[3] = (_Float16)v.w;
      *(f16x4*)(xh + idx) = h4;
    }
    float(*t)[33] = (float(*)[33])smraw;
    for (int u = 0; u < 2; ++u) {
      __syncthreads();
      int wu = bid * 2 + u;     // [0,1024)
      int z = wu >> 8, by = (wu >> 4) & 15, bx = wu & 15;
      const float* w = z == 0 ? wq : z == 1 ? wk : z == 2 ? wv : wo;
      int r0 = by * 32, c0 = bx * 32;
#pragma unroll
      for (int p = 0; p < 4; ++p) {
        int e = p * 256 + tid;
        t[e >> 5][e & 31] =
            w[(size_t)(r0 + (e >> 5)) * D_MODEL + c0 + (e & 31)];
      }
      __syncthreads();
      _Float16* o = wT + (size_t)z * D_MODEL * D_MODEL;
#pragma unroll
      for (int p = 0; p < 4; ++p) {
        int e = p * 256 + tid;
        o[(size_t)(c0 + (e >> 5)) * D_MODEL + r0 + (e & 31)] =
            (_Float16)t[e & 31][e >> 5];
      }
      if ((wu & 255) == 0 && z < 3) {
        const float* bb = z == 0 ? bq : z == 1 ? bk : bv;
#pragma unroll
        for (int p = 0; p < 2; ++p)
          bias3[z * D_MODEL + p * 256 + tid] = bb[p * 256 + tid];
      }
    }
  }
  gridbar(flags, 0, tid);

  // ---- phase 1: QKV GEMM (384 units; BM=BN=128)
  if (bid < 384) {
    int nx = bid & 3, ny = (bid >> 2) & 31, z = bid >> 7;
    gemm_phase<0, 128, 128, 2>(
        smraw, xh, wT + (size_t)z * D_MODEL * D_MODEL, bias3 + z * D_MODEL,
        QKV + (size_t)z * M_ROWS * D_MODEL, ny * 128, nx * 128, tid);
  }
  gridbar(flags, 1, tid);

  // ---- phase 2: local attention (512 units; exactly 1 per block)
  {
    int b = bid >> 8, r = bid & 255;
    attn_phase(smraw, QKV, QKV + (size_t)M_ROWS * D_MODEL,
               QKV + (size_t)2 * M_ROWS * D_MODEL, att, b, r >> 5,
               (r & 31) * 64, tid);
  }
  gridbar(flags, 2, tid);

  // ---- phase 3: out GEMM (256 units; BM=64, BN=128)
  if (bid < 256) {
    int ny = bid >> 2, nx = bid & 3;
    gemm_phase<1, 64, 128, 1>(smraw, att,
                              wT + (size_t)3 * D_MODEL * D_MODEL, bo, out,
                              ny * 64, nx * 128, tid);
  }
}

// ---------------------------------------------------------------- launch
extern "C" void kernel_launch(void* const* d_in, const int* in_sizes, int n_in,
                              void* d_out, int out_size, void* d_ws,
                              size_t ws_size, hipStream_t stream) {
  const float* x = (const float*)d_in[0];
  const float* wq = (const float*)d_in[1];
  const float* bq = (const float*)d_in[2];
  const float* wk = (const float*)d_in[3];
  const float* bk = (const float*)d_in[4];
  const float* wv = (const float*)d_in[5];
  const float* bv = (const float*)d_in[6];
  const float* wo = (const float*)d_in[7];
  const float* bo = (const float*)d_in[8];
  float* out = (float*)d_out;

  char* ws = (char*)d_ws;
  _Float16* xh = (_Float16*)(ws);                    // 4 MB
  _Float16* wT = (_Float16*)(ws + (4 << 20));        // 2 MB
  float* bias3 = (float*)(ws + (6 << 20));           // 6 KB
  _Float16* QKV = (_Float16*)(ws + (6 << 20) + (64 << 10));  // 12 MB
  _Float16* att = (_Float16*)(ws + (20 << 20));      // 4 MB
  int* flags = (int*)(ws + (24 << 20));              // 3 slots x 128B

  hipMemsetAsync(flags, 0, 3 * 32 * sizeof(int), stream);
  void* args[] = {(void*)&x,   (void*)&wq,  (void*)&wk,  (void*)&wv,
                  (void*)&wo,  (void*)&bq,  (void*)&bk,  (void*)&bv,
                  (void*)&bo,  (void*)&out, (void*)&xh,  (void*)&wT,
                  (void*)&bias3, (void*)&QKV, (void*)&att, (void*)&flags};
  hipLaunchKernel((const void*)mega, dim3(NBLK), dim3(256), args, 0, stream);
}

// Round 11
// 44.052 us; speedup vs baseline: 3.5508x; 3.5508x over previous
//
#include <hip/hip_runtime.h>

using f16x8 = __attribute__((ext_vector_type(8))) _Float16;
using f16x4 = __attribute__((ext_vector_type(4))) _Float16;
using f32x4 = __attribute__((ext_vector_type(4))) float;

#define T_SEQ 2048
#define D_MODEL 512
#define NH 8
#define HD 64
#define NB 2
#define M_ROWS (NB * T_SEQ)   // 4096

// async global->LDS, 16B per lane. LDS dest must be wave-uniform base;
// HW adds lane*16. Source is per-lane.
#define GLOAD_LDS16(g, l)                                              \
  __builtin_amdgcn_global_load_lds(                                    \
      (const __attribute__((address_space(1))) void*)(g),              \
      (__attribute__((address_space(3))) void*)(l), 16, 0, 0)

// ---------------------------------------------------------------- converts
// fused: blocks [0,2048) convert x -> fp16; blocks [2048,3072) transpose-
// convert the 4 weight matrices and copy qkv biases.
__global__ __launch_bounds__(256) void cvt_all(
    const float* __restrict__ x, const float* __restrict__ wq,
    const float* __restrict__ wk, const float* __restrict__ wv,
    const float* __restrict__ wo, const float* __restrict__ bq,
    const float* __restrict__ bk, const float* __restrict__ bv,
    _Float16* __restrict__ xh, _Float16* __restrict__ wT,
    float* __restrict__ bias3) {
  int bid = blockIdx.x;
  int i = threadIdx.x;
  if (bid < 2048) {
    int idx = (bid * 256 + i) * 4;
    float4 v = *(const float4*)(x + idx);
    f16x4 h;
    h[0] = (_Float16)v.x; h[1] = (_Float16)v.y;
    h[2] = (_Float16)v.z; h[3] = (_Float16)v.w;
    *(f16x4*)(xh + idx) = h;
    return;
  }
  bid -= 2048;
  const int z = bid >> 8;
  const int by = (bid >> 4) & 15;
  const int bx = bid & 15;
  const float* w = z == 0 ? wq : z == 1 ? wk : z == 2 ? wv : wo;
  __shared__ float t[32][33];
  int r0 = by * 32, c0 = bx * 32;
#pragma unroll
  for (int p = 0; p < 4; ++p) {
    int e = p * 256 + i;
    t[e >> 5][e & 31] = w[(size_t)(r0 + (e >> 5)) * D_MODEL + c0 + (e & 31)];
  }
  __syncthreads();
  _Float16* o = wT + (size_t)z * D_MODEL * D_MODEL;
#pragma unroll
  for (int p = 0; p < 4; ++p) {
    int e = p * 256 + i;
    o[(size_t)(c0 + (e >> 5)) * D_MODEL + r0 + (e & 31)] =
        (_Float16)t[e & 31][e >> 5];
  }
  if (bx == 0 && by == 0 && z < 3) {
    const float* bb = z == 0 ? bq : z == 1 ? bk : bv;
#pragma unroll
    for (int p = 0; p < 2; ++p)
      bias3[z * D_MODEL + p * 256 + i] = bb[p * 256 + i];
  }
}

// ---------------------------------------------------------------- GEMM phase
// C[m][n] = sum_k A[m][k] * Bt[n][k] + bias[n]
// 3-buffer 2-deep prefetch, counted vmcnt (T3+T4); LDS XOR-swizzle via
// pre-swizzled global source + swizzled reads (T2 both-sides involution).
template <int OUT_F32, int BM, int BN, int WR>
__device__ __forceinline__ void gemm_phase(
    char* smraw, const _Float16* __restrict__ A,
    const _Float16* __restrict__ Bt, const float* __restrict__ bias,
    void* __restrict__ outBase, int m0, int n0, int tid) {
  constexpr int WC = 4 / WR;
  constexpr int MF = BM / WR / 16;
  constexpr int NF = BN / WC / 16;
  constexpr int NT = D_MODEL / 32;            // 16 K-steps
  constexpr int LPS = BM / 64 + BN / 64;      // gload_lds per thread/stage
  _Float16* At = (_Float16*)smraw;
  _Float16* Bts = (_Float16*)(smraw + 3 * BM * 32 * 2);
  const int l = tid & 63;
  const int wv = tid >> 6;
  const int wm = wv / WC, wn = wv % WC;
  const int r16 = l & 15, g4 = l >> 4;
  f32x4 acc[MF][NF] = {};

  auto stage = [&](int bb, int k0) {
#pragma unroll
    for (int cc = 0; cc < BM / 64; ++cc) {
      int c = tid + cc * 256;
      int row = c >> 2, sp = (c & 3) ^ (row & 3);
      GLOAD_LDS16(&A[(size_t)(m0 + row) * D_MODEL + k0 + sp * 8],
                  &At[bb * BM * 32 + (c - l) * 8]);
    }
#pragma unroll
    for (int cc = 0; cc < BN / 64; ++cc) {
      int c = tid + cc * 256;
      int row = c >> 2, sp = (c & 3) ^ (row & 3);
      GLOAD_LDS16(&Bt[(size_t)(n0 + row) * D_MODEL + k0 + sp * 8],
                  &Bts[bb * BN * 32 + (c - l) * 8]);
    }
  };
  auto compute = [&](int bb) {
    f16x8 a[MF], b[NF];
#pragma unroll
    for (int mf = 0; mf < MF; ++mf) {
      int row = wm * (BM / WR) + mf * 16 + r16;
      a[mf] =
          *(const f16x8*)&At[bb * BM * 32 + row * 32 + (g4 ^ (row & 3)) * 8];
    }
#pragma unroll
    for (int nf = 0; nf < NF; ++nf) {
      int row = wn * (BN / WC) + nf * 16 + r16;
      b[nf] =
          *(const f16x8*)&Bts[bb * BN * 32 + row * 32 + (g4 ^ (row & 3)) * 8];
    }
#pragma unroll
    for (int mf = 0; mf < MF; ++mf)
#pragma unroll
      for (int nf = 0; nf < NF; ++nf)
        acc[mf][nf] = __builtin_amdgcn_mfma_f32_16x16x32_f16(
            a[mf], b[nf], acc[mf][nf], 0, 0, 0);
  };

  stage(0, 0);
  stage(1, 32);
#pragma unroll
  for (int t = 0; t < NT; ++t) {
    if (t + 1 < NT)
      asm volatile("s_waitcnt vmcnt(%0)" ::"n"(LPS) : "memory");
    else
      asm volatile("s_waitcnt vmcnt(0)" ::: "memory");
    __builtin_amdgcn_s_barrier();
    compute(t % 3);
    if (t + 2 < NT) stage((t + 2) % 3, (t + 2) * 32);
  }

#pragma unroll
  for (int mf = 0; mf < MF; ++mf) {
#pragma unroll
    for (int nf = 0; nf < NF; ++nf) {
      int col = n0 + wn * (BN / WC) + nf * 16 + r16;
      float bs = bias[col];
#pragma unroll
      for (int r = 0; r < 4; ++r) {
        int rowi = m0 + wm * (BM / WR) + mf * 16 + g4 * 4 + r;
        float v = acc[mf][nf][r] + bs;
        if (OUT_F32)
          ((float*)outBase)[(size_t)rowi * D_MODEL + col] = v;
        else
          ((_Float16*)outBase)[(size_t)rowi * D_MODEL + col] = (_Float16)v;
      }
    }
  }
}

// QKV GEMM: BM=128, BN=64 -> grid (8,32,3) = 768 blocks = 3/CU exact
// (vs 384 = 1.5/CU: removes the half-empty second dispatch wave).
__global__ __launch_bounds__(256) void k_gemm_qkv(
    const _Float16* __restrict__ A, const _Float16* __restrict__ BtBase,
    const float* __restrict__ biasBase, _Float16* __restrict__ outBase) {
  __shared__ __align__(16) char sm[36864];
  int z = blockIdx.z;
  gemm_phase<0, 128, 64, 2>(
      sm, A, BtBase + (size_t)z * D_MODEL * D_MODEL, biasBase + z * D_MODEL,
      outBase + (size_t)z * M_ROWS * D_MODEL, blockIdx.y * 128,
      blockIdx.x * 64, threadIdx.x);
}

// out GEMM: BM=64, BN=128 -> grid (4,64) = 256 blocks = 1/CU exact.
__global__ __launch_bounds__(256) void k_out(
    const _Float16* __restrict__ att, const _Float16* __restrict__ woT,
    const float* __restrict__ bo, float* __restrict__ out) {
  __shared__ __align__(16) char sm[36864];
  gemm_phase<1, 64, 128, 1>(sm, att, woT, bo, out, blockIdx.y * 64,
                            blockIdx.x * 128, threadIdx.x);
}

// ---------------------------------------------------------------- attention
// one block per (b, h, 64-query tile). keys j=0..127 map to t = t0-32+j.
// window for query ql: j in [ql, ql+64]. out-of-sequence keys are zero
// (score 0 participates in softmax denom = reference zero-pad semantics).
// Q in registers; K XOR-swizzled via pre-swizzled source; Vt/Ps padded 136.
__global__ __launch_bounds__(256) void k_attn(
    const _Float16* __restrict__ Q, const _Float16* __restrict__ K,
    const _Float16* __restrict__ V, _Float16* __restrict__ att) {
  const int t0 = blockIdx.x * 64;
  const int h = blockIdx.y;
  const int b = blockIdx.z;
  const int k0 = t0 - 32;
  __shared__ _Float16 Ks[128 * 64];
  __shared__ _Float16 Vt[64 * 136];
  __shared__ _Float16 Ps[64 * 136];
  const int tid = threadIdx.x;
  const int l = tid & 63;
  const int wv = tid >> 6;
  const int r16 = l & 15, g4 = l >> 4;
  const size_t colbase = (size_t)h * HD;
  // Q fragments straight to registers
  f16x8 qf[2];
#pragma unroll
  for (int kk = 0; kk < 2; ++kk)
    qf[kk] = *(const f16x8*)&Q[(size_t)(b * T_SEQ + t0 + wv * 16 + r16) *
                                   D_MODEL + colbase + kk * 32 + g4 * 8];
  // stage K (128 rows): interior DMA (swizzled source), edge reg path
  const bool interior = (k0 >= 0) && (k0 + 128 <= T_SEQ);
  if (interior) {
#pragma unroll
    for (int cc = 0; cc < 4; ++cc) {
      int c = tid + cc * 256;
      int row = c >> 3, part = c & 7;
      int sp = part ^ (row & 7);
      GLOAD_LDS16(
          &K[(size_t)(b * T_SEQ + k0 + row) * D_MODEL + colbase + sp * 8],
          &Ks[(c - l) * 8]);
    }
  } else {
#pragma unroll
    for (int cc = 0; cc < 4; ++cc) {
      int c = tid + cc * 256;
      int row = c >> 3, part = c & 7;
      int t = k0 + row;
      f16x8 v = {};
      if (t >= 0 && t < T_SEQ)
        v = *(const f16x8*)&K[(size_t)(b * T_SEQ + t) * D_MODEL + colbase +
                              part * 8];
      *(f16x8*)&Ks[row * 64 + (part ^ (row & 7)) * 8] = v;
    }
  }
  // stage V transposed: Vt[dd][key], padded stride 136
#pragma unroll
  for (int cc = 0; cc < 4; ++cc) {
    int c = tid + cc * 256;
    int row = c >> 3, part = c & 7;
    int t = k0 + row;
    f16x8 v = {};
    if (t >= 0 && t < T_SEQ)
      v = *(const f16x8*)&V[(size_t)(b * T_SEQ + t) * D_MODEL + colbase +
                            part * 8];
#pragma unroll
    for (int j = 0; j < 8; ++j) Vt[(part * 8 + j) * 136 + row] = v[j];
  }
  __syncthreads();
  // S = Q K^T : wave wv owns query rows [wv*16, wv*16+16), all 128 keys
  f32x4 s[8] = {};
#pragma unroll
  for (int kk = 0; kk < 2; ++kk) {
    int p = kk * 4 + g4;
#pragma unroll
    for (int nf = 0; nf < 8; ++nf) {
      f16x8 bb =
          *(const f16x8*)&Ks[(nf * 16 + r16) * 64 + (p ^ (r16 & 7)) * 8];
      s[nf] =
          __builtin_amdgcn_mfma_f32_16x16x32_f16(qf[kk], bb, s[nf], 0, 0, 0);
    }
  }
  // softmax: lane's rows ql = wv*16 + g4*4 + r ; cols j = nf*16 + r16
#pragma unroll
  for (int r = 0; r < 4; ++r) {
    int ql = wv * 16 + g4 * 4 + r;
    float vals[8];
    float m = -1e30f;
#pragma unroll
    for (int nf = 0; nf < 8; ++nf) {
      int j = nf * 16 + r16;
      bool in = (j >= ql) && (j <= ql + 64);
      float sv = in ? s[nf][r] * 0.125f : -1e30f;
      vals[nf] = sv;
      m = fmaxf(m, sv);
    }
#pragma unroll
    for (int off = 1; off < 16; off <<= 1) m = fmaxf(m, __shfl_xor(m, off, 64));
    float e[8];
    float sum = 0.f;
#pragma unroll
    for (int nf = 0; nf < 8; ++nf) {
      float ev = (vals[nf] > -1e29f) ? __expf(vals[nf] - m) : 0.f;
      e[nf] = ev;
      sum += ev;
    }
#pragma unroll
    for (int off = 1; off < 16; off <<= 1) sum += __shfl_xor(sum, off, 64);
    float inv = 1.f / sum;
#pragma unroll
    for (int nf = 0; nf < 8; ++nf)
      Ps[ql * 136 + nf * 16 + r16] = (_Float16)(e[nf] * inv);
  }
  __syncthreads();
  // O = P V : wave wv owns query rows [wv*16, wv*16+16), dims 0..63
  f32x4 o[4] = {};
#pragma unroll
  for (int kk = 0; kk < 4; ++kk) {
    f16x8 a = *(const f16x8*)&Ps[(wv * 16 + r16) * 136 + kk * 32 + g4 * 8];
#pragma unroll
    for (int nf = 0; nf < 4; ++nf) {
      f16x8 bb = *(const f16x8*)&Vt[(nf * 16 + r16) * 136 + kk * 32 + g4 * 8];
      o[nf] = __builtin_amdgcn_mfma_f32_16x16x32_f16(a, bb, o[nf], 0, 0, 0);
    }
  }
#pragma unroll
  for (int nf = 0; nf < 4; ++nf)
#pragma unroll
    for (int r = 0; r < 4; ++r) {
      int row = t0 + wv * 16 + g4 * 4 + r;
      int col = nf * 16 + r16;
      att[(size_t)(b * T_SEQ + row) * D_MODEL + colbase + col] =
          (_Float16)o[nf][r];
    }
}

// ---------------------------------------------------------------- launch
extern "C" void kernel_launch(void* const* d_in, const int* in_sizes, int n_in,
                              void* d_out, int out_size, void* d_ws,
                              size_t ws_size, hipStream_t stream) {
  const float* x = (const float*)d_in[0];
  const float* wq = (const float*)d_in[1];
  const float* bq = (const float*)d_in[2];
  const float* wk = (const float*)d_in[3];
  const float* bk = (const float*)d_in[4];
  const float* wv = (const float*)d_in[5];
  const float* bv = (const float*)d_in[6];
  const float* wo = (const float*)d_in[7];
  const float* bo = (const float*)d_in[8];
  float* out = (float*)d_out;

  char* ws = (char*)d_ws;
  _Float16* xh = (_Float16*)(ws);                    // 4 MB (reused as att)
  _Float16* wT = (_Float16*)(ws + (4 << 20));        // 2 MB
  float* bias3 = (float*)(ws + (6 << 20));           // 6 KB
  _Float16* QKV = (_Float16*)(ws + (6 << 20) + (64 << 10));  // 12 MB
  _Float16* att = xh;                                // reuse x-half region

  cvt_all<<<3072, 256, 0, stream>>>(x, wq, wk, wv, wo, bq, bk, bv, xh, wT,
                                    bias3);
  k_gemm_qkv<<<dim3(8, 32, 3), 256, 0, stream>>>(xh, wT, bias3, QKV);
  const _Float16* Qm = QKV;
  const _Float16* Km = QKV + (size_t)M_ROWS * D_MODEL;
  const _Float16* Vm = Km + (size_t)M_ROWS * D_MODEL;
  k_attn<<<dim3(32, 8, 2), 256, 0, stream>>>(Qm, Km, Vm, att);
  k_out<<<dim3(4, 64), 256, 0, stream>>>(
      att, wT + (size_t)3 * D_MODEL * D_MODEL, bo, out);
}